// Round 6
// baseline (184.672 us; speedup 1.0000x reference)
//
#include <hip/hip_runtime.h>

// ---------------------------------------------------------------------------
// Attention_52424370815683: B=2, S=2048, D=1024, H=16, hd=64. f32 I/O.
//   k0: convert x|qkv_w|proj_w f32 -> bf16 (single merged launch)
//   k1: qkv GEMM, 128x128 BK=64 dbuf 2-phase, 256 thr -> q[b,h,s,d],
//       k/v written PRE-FRAGMENTED for the attn MFMA32 frag layout
//       (k pre-scaled by hd^-0.5*log2e folded in)
//   k2: flash attention, reg-frag K/V, in-block split-K. Occupancy is
//       register-capped at 2 waves/SIMD (arch-VGPR 120 + ~64 AGPR = 184/wave
//       -> 512/184 = 2; r4/r5 proved grid size can't change this). So the
//       lever is per-wave VALU density: fzero C-in (no per-tile acc init),
//       v_cvt_pk_bf16_f32 asm (no software bf16 round), packed f32x2 lsum.
//   k3: out(f32) = attn @ proj_w^T + proj_b, 128x64 tiles, 2-phase dbuf.
//
// Pre-fragmented K layout (elements, per bh):  ((kt*2 + t)*2048) + s*512
//   + lane*8, lane = hi*32+l31 holds K[key=kt*64+t*32+l31][d=s*16+hi*8..+7].
// Pre-fragmented V layout: ((kt*2 + dt)*2048) + s*512 + lane*8, lane holds
//   Vt[d=dt*32+l31][key=kt*64+s*16+hi*8..+7].  8KB per kt tile each.
// ---------------------------------------------------------------------------

typedef __bf16 bf16_8 __attribute__((ext_vector_type(8)));
typedef __bf16 bf16_4 __attribute__((ext_vector_type(4)));
typedef __bf16 bf16_2 __attribute__((ext_vector_type(2)));
typedef float floatx2 __attribute__((ext_vector_type(2)));
typedef float floatx4 __attribute__((ext_vector_type(4)));
typedef float floatx16 __attribute__((ext_vector_type(16)));
typedef unsigned uintx4 __attribute__((ext_vector_type(4)));

#define MFMA16 __builtin_amdgcn_mfma_f32_16x16x32_bf16
#define MFMA32 __builtin_amdgcn_mfma_f32_32x32x16_bf16
#define CSCALE 0.1803368801111204f   // hd^-0.5 * log2(e)
#define EXP2R  __builtin_amdgcn_exp2f   // bare v_exp_f32 (no OCML denorm fixup)

__device__ __forceinline__ void gld16(const __bf16* g, __bf16* l) {
    __builtin_amdgcn_global_load_lds(
        (const __attribute__((address_space(1))) void*)g,
        (__attribute__((address_space(3))) void*)l, 16, 0, 0);
}

__device__ __forceinline__ unsigned pk_bf16(float a, float b) {
    bf16_2 t;
    t[0] = (__bf16)a; t[1] = (__bf16)b;
    return __builtin_bit_cast(unsigned, t);
}

// single-instruction packed f32->bf16 (RNE), lo = a, hi = b
__device__ __forceinline__ unsigned cvtpk_bf16(float a, float b) {
    unsigned d;
    __asm__("v_cvt_pk_bf16_f32 %0, %1, %2" : "=v"(d) : "v"(a), "v"(b));
    return d;
}

// v_permlane32_swap_b32: after the op, a = {a_lo, b_lo}, b = {a_hi, b_hi}
__device__ __forceinline__ void pl32swap(unsigned& a, unsigned& b) {
    __asm__ __volatile__("v_permlane32_swap_b32 %0, %1" : "+v"(a), "+v"(b));
}

// ---------------------------------------------------------------------------
// Kernel 0: merged f32 -> bf16 convert for x (1M f4), qkv_w (768K), proj_w
// (256K). Grid exactly 2M float4s / 256.
// ---------------------------------------------------------------------------
__global__ __launch_bounds__(256) void cvt_all(
    const float* __restrict__ x, const float* __restrict__ w1,
    const float* __restrict__ w2,
    __bf16* __restrict__ xb, __bf16* __restrict__ w1b, __bf16* __restrict__ w2b)
{
    const int i = blockIdx.x * 256 + threadIdx.x;     // float4 index
    const float* src; __bf16* dst; int off;
    if (i < (1 << 20))                  { src = x;  dst = xb;  off = i; }
    else if (i < (1 << 20) + 786432)    { src = w1; dst = w1b; off = i - (1 << 20); }
    else                                { src = w2; dst = w2b; off = i - (1 << 20) - 786432; }
    float4 v = ((const float4*)src)[off];
    bf16_4 o;
    o[0] = (__bf16)v.x; o[1] = (__bf16)v.y; o[2] = (__bf16)v.z; o[3] = (__bf16)v.w;
    ((bf16_4*)dst)[off] = o;
}

// ---------------------------------------------------------------------------
// Kernel 1: QKV GEMM. M=4096, N=3072, K=1024. grid (24,32), 256 threads,
// 128x128 tile, BK=64, double-buffered LDS (64 KB -> 2 blocks/CU), 2-phase:
// stage(k+1) -> compute(k) -> vmcnt(0)+barrier (1 barrier/step).
// q/k blocks (c<2): swapped operands -> feature-contiguous packed stores.
// k/v epilogues write the pre-fragmented attention layouts (see header).
// ---------------------------------------------------------------------------
__global__ __launch_bounds__(256) void qkv_gemm(
    const __bf16* __restrict__ X, const __bf16* __restrict__ W,
    __bf16* __restrict__ q_ws, __bf16* __restrict__ k_ws, __bf16* __restrict__ vt_ws)
{
    __shared__ __align__(16) __bf16 S[2][2][128 * 64];  // [buf][A/B] 64 KB

    const int tid = threadIdx.x, lane = tid & 63, wv = tid >> 6;
    const int quad = lane >> 4, l15 = lane & 15;
    const int wm = (wv >> 1) * 64, wn = (wv & 1) * 64;
    const int m0 = blockIdx.y * 128, n0 = blockIdx.x * 128;
    const int c = n0 >> 10;                         // 0=q 1=k 2=v (block-uniform)

    // A/B row bases (both K-major, stride 1024). c<2: swapped (rows=feature).
    const __bf16* Abase;
    const __bf16* Bbase;
    if (c == 2) { Abase = X + (size_t)m0 * 1024; Bbase = W + (size_t)n0 * 1024; }
    else        { Abase = W + (size_t)n0 * 1024; Bbase = X + (size_t)m0 * 1024; }

    const int srow = tid >> 3, skc = tid & 7;       // staging: loop-invariant
    const int ssw  = (skc ^ (srow & 7)) * 8;

#define QKV_STAGE(buf, k0)                                                     \
    {                                                                          \
        _Pragma("unroll")                                                      \
        for (int itg = 0; itg < 4; ++itg) {                                    \
            const int cc = itg * 256 + tid;                                    \
            const int row = srow + itg * 32;                                   \
            gld16(Abase + row * 1024 + (k0) + ssw, &S[buf][0][cc * 8]);        \
            gld16(Bbase + row * 1024 + (k0) + ssw, &S[buf][1][cc * 8]);        \
        }                                                                      \
    }

    floatx4 acc[4][4] = {};
    QKV_STAGE(0, 0)
    __syncthreads();

#pragma unroll 1
    for (int kk = 0; kk < 16; ++kk) {
        const int cur = kk & 1;
        if (kk < 15) QKV_STAGE(cur ^ 1, (kk + 1) * 64)

        const __bf16* As = S[cur][0];
        const __bf16* Bs = S[cur][1];
#pragma unroll
        for (int ks = 0; ks < 2; ++ks) {
            bf16_8 af[4], bf[4];
#pragma unroll
            for (int mt = 0; mt < 4; ++mt) {
                int r = wm + mt * 16 + l15;
                af[mt] = *(const bf16_8*)&As[r * 64 + (((ks * 4 + quad) ^ (r & 7)) * 8)];
            }
#pragma unroll
            for (int nt = 0; nt < 4; ++nt) {
                int r = wn + nt * 16 + l15;
                bf[nt] = *(const bf16_8*)&Bs[r * 64 + (((ks * 4 + quad) ^ (r & 7)) * 8)];
            }
#pragma unroll
            for (int mt = 0; mt < 4; ++mt)
#pragma unroll
                for (int nt = 0; nt < 4; ++nt)
                    acc[mt][nt] = MFMA16(af[mt], bf[nt], acc[mt][nt], 0, 0, 0);
        }

        if (kk < 15) {
            __asm__ __volatile__("s_waitcnt vmcnt(0)" ::: "memory");
            __syncthreads();
        }
    }

    if (c == 2) {
        // V: D rows = token(key), cols = feature. Pack 4 consecutive keys.
#pragma unroll
        for (int mt = 0; mt < 4; ++mt) {
            const int mbase = m0 + wm + mt * 16 + quad * 4;   // token, 4-aligned
            const int b = mbase >> 11, key0 = mbase & 2047;
#pragma unroll
            for (int nt = 0; nt < 4; ++nt) {
                const int n = n0 + wn + nt * 16 + l15;
                const int h = (n >> 6) & 15, d = n & 63;
                const int dt = d >> 5, l31v = d & 31;
                bf16_4 pk;
#pragma unroll
                for (int r = 0; r < 4; ++r) pk[r] = (__bf16)acc[mt][nt][r];
                const size_t off =
                    (((size_t)(b * 16 + h) * 32 + (key0 >> 6)) * 2 + dt) * 2048
                    + ((key0 >> 4) & 3) * 512
                    + (((key0 >> 3) & 1) * 32 + l31v) * 8 + (key0 & 7);
                *(bf16_4*)&vt_ws[off] = pk;
            }
        }
    } else {
        const float scale = (c == 1) ? CSCALE : 1.0f;
#pragma unroll
        for (int mt = 0; mt < 4; ++mt) {
            const int nn = n0 + wm + mt * 16 + quad * 4;      // feature, 4-aligned
            const int h = (nn >> 6) & 15, d0 = nn & 63;
#pragma unroll
            for (int nt = 0; nt < 4; ++nt) {
                const int token = m0 + wn + nt * 16 + l15;
                const int b = token >> 11, key = token & 2047;
                bf16_4 pk;
#pragma unroll
                for (int r = 0; r < 4; ++r) pk[r] = (__bf16)(acc[mt][nt][r] * scale);
                if (c == 0) {
                    *(bf16_4*)&q_ws[((size_t)(b * 16 + h) * 2048 + key) * 64 + d0] = pk;
                } else {
                    const size_t off =
                        (((size_t)(b * 16 + h) * 32 + (key >> 6)) * 2 + ((key >> 5) & 1)) * 2048
                        + (d0 >> 4) * 512
                        + (((d0 >> 3) & 1) * 32 + (key & 31)) * 8 + (d0 & 7);
                    *(bf16_4*)&k_ws[off] = pk;
                }
            }
        }
    }
#undef QKV_STAGE
}

// ---------------------------------------------------------------------------
// Kernel 2: flash attention, reg-frag K/V, in-block split-K.
// grid (32,32) = 1024 blocks x 4 waves; register-capped 2 waves/SIMD.
// Wave (qtile=w&1, keyhalf=w>>1): 32 q x 1024 keys (16 tiles of 64). No
// main-loop barriers; one __syncthreads + f32 LDS merge (no-max softmax).
// XCD remap: linear%8 owns 4 bh -> L2-resident K/V (FETCH == unique 12 MB).
// VALU diet (r6): fzero C-in, v_cvt_pk_bf16_f32 asm, packed f32x2 lsum.
// ---------------------------------------------------------------------------
__global__ __launch_bounds__(256) void attn_kernel(
    const __bf16* __restrict__ q_ws, const __bf16* __restrict__ k_ws,
    const __bf16* __restrict__ vt_ws, __bf16* __restrict__ attn_ws)
{
    __shared__ __align__(16) floatx4 comb[2][8][64];    // [qtile][j][lane] 16 KB
    __shared__ float lcomb[2][64];

    const int tid = threadIdx.x, lane = tid & 63, w = tid >> 6;   // w 0..3
    const int l31 = lane & 31, hi = lane >> 5;
    const int qtile = w & 1, keyhalf = w >> 1;

    // XCD-aware remap: linear % 8 = XCD; each XCD owns bh in [4x, 4x+4).
    const int linear = blockIdx.x + (blockIdx.y << 5);
    const int r = linear >> 3;
    const int bh = ((linear & 7) << 2) + (r & 3);
    const int qblk = r >> 2;                            // 0..31
    const int q0 = qblk * 64 + qtile * 32;

    const __bf16* __restrict__ qp  = q_ws  + (size_t)bh * (2048 * 64);
    const __bf16* __restrict__ kb0 = k_ws  + (size_t)bh * 131072 + keyhalf * 65536;
    const __bf16* __restrict__ kb1 = kb0 + 2048;
    const __bf16* __restrict__ vb0 = vt_ws + (size_t)bh * 131072 + keyhalf * 65536;
    const __bf16* __restrict__ vb1 = vb0 + 2048;

    const int vo = lane * 8;                // per-lane element offset (32-bit)

    // Q B-frags (4 k-steps of 16), held in registers all loop
    bf16_8 qf[4];
    {
        const int qrow = q0 + l31;
#pragma unroll
        for (int s = 0; s < 4; ++s)
            qf[s] = *(const bf16_8*)&qp[qrow * 64 + s * 16 + hi * 8];
    }

    floatx16 oacc[2] = {};                  // [d-tile] O^T accumulators
    floatx2 ls2[4] = {};                    // packed row-sum partials
    const floatx16 fzero = {};              // persistent zero C-in (hoisted)

    bf16_8 ka[8], kb[8], va[8];
#pragma unroll
    for (int u = 0; u < 8; ++u)             // prologue: K tile 0 of this half
        ka[u] = *(const bf16_8*)&(u < 4 ? kb0 : kb1)[vo + (u & 3) * 512];

    // One 64-key tile. KC = current K frags, KN = prefetch target.
    // (Final prefetch reads 8KB past this wave's K half -> other half /
    //  next bh's K / vt_ws, all allocated; value never consumed.)
#define ATTN_TILE(KC, KN, KT)                                                  \
    {                                                                          \
        const int ko  = (KT) * 4096 + vo;                                      \
        const int kon = ko + 4096;                                             \
        _Pragma("unroll")                                                      \
        for (int u = 0; u < 8; ++u)   /* V(t): covered by QK+exp phases */     \
            va[u] = *(const bf16_8*)&(u < 4 ? vb0 : vb1)[ko + (u & 3) * 512];  \
        floatx16 sacc[2];                                                      \
        __builtin_amdgcn_s_setprio(1);                                         \
        sacc[0] = MFMA32(KC[0], qf[0], fzero, 0, 0, 0);                        \
        sacc[1] = MFMA32(KC[4], qf[0], fzero, 0, 0, 0);                        \
        _Pragma("unroll")                                                      \
        for (int s = 1; s < 4; ++s) {                                          \
            sacc[0] = MFMA32(KC[s],     qf[s], sacc[0], 0, 0, 0);              \
            sacc[1] = MFMA32(KC[4 + s], qf[s], sacc[1], 0, 0, 0);              \
        }                                                                      \
        __builtin_amdgcn_s_setprio(0);                                         \
        _Pragma("unroll")                                                      \
        for (int u = 0; u < 8; ++u)   /* K(t+1) prefetch */                    \
            KN[u] = *(const bf16_8*)&(u < 4 ? kb0 : kb1)[kon + (u & 3) * 512]; \
        unsigned D[2][4][2];                                                   \
        _Pragma("unroll")                                                      \
        for (int t = 0; t < 2; ++t)                                            \
            _Pragma("unroll")                                                  \
            for (int j = 0; j < 4; ++j)                                        \
                _Pragma("unroll")                                              \
                for (int e = 0; e < 2; ++e) {                                  \
                    float pa = EXP2R(sacc[t][j * 4 + e * 2]);                  \
                    float pb = EXP2R(sacc[t][j * 4 + e * 2 + 1]);              \
                    floatx2 p2; p2[0] = pa; p2[1] = pb;                        \
                    ls2[t * 2 + e] += p2;        /* v_pk_add_f32 */            \
                    D[t][j][e] = cvtpk_bf16(pa, pb);                           \
                }                                                              \
        __builtin_amdgcn_s_setprio(1);                                         \
        _Pragma("unroll")                                                      \
        for (int s = 0; s < 4; ++s) {                                          \
            const int t = s >> 1, b2 = (s & 1) * 2;                            \
            unsigned x0 = D[t][b2][0], y0 = D[t][b2 + 1][0];                   \
            unsigned x1 = D[t][b2][1], y1 = D[t][b2 + 1][1];                   \
            pl32swap(x0, y0);                                                  \
            pl32swap(x1, y1);                                                  \
            uintx4 uu; uu[0] = x0; uu[1] = x1; uu[2] = y0; uu[3] = y1;         \
            const bf16_8 pf = __builtin_bit_cast(bf16_8, uu);                  \
            oacc[0] = MFMA32(va[s],     pf, oacc[0], 0, 0, 0);                 \
            oacc[1] = MFMA32(va[4 + s], pf, oacc[1], 0, 0, 0);                 \
        }                                                                      \
        __builtin_amdgcn_s_setprio(0);                                         \
    }

#pragma unroll 1
    for (int it = 0; it < 8; ++it) {
        ATTN_TILE(ka, kb, (it * 2))
        ATTN_TILE(kb, ka, (it * 2 + 1))
    }
#undef ATTN_TILE

    // ---- this wave's row-sums over its 1024 keys (combine hi halves)
    const floatx2 lv = (ls2[0] + ls2[1]) + (ls2[2] + ls2[3]);
    const float lsum = lv[0] + lv[1];
    const float lw = lsum + __shfl_xor(lsum, 32, 64);

    // ---- split-K merge: keyhalf=1 waves dump f32 O + l to LDS; keyhalf=0
    // waves add, normalize, store. Lane-aligned (same q<->lane mapping).
    if (keyhalf == 1) {
#pragma unroll
        for (int dt = 0; dt < 2; ++dt)
#pragma unroll
            for (int g = 0; g < 4; ++g) {
                floatx4 v4;
#pragma unroll
                for (int r4 = 0; r4 < 4; ++r4) v4[r4] = oacc[dt][g * 4 + r4];
                comb[qtile][dt * 4 + g][lane] = v4;
            }
        lcomb[qtile][lane] = lw;
    }
    __syncthreads();
    if (keyhalf == 0) {
        // oacc C32 layout: col = q = lane&31, row d = (r&3)+8*(r>>2)+4*hi.
        const int b = bh >> 4, h = bh & 15;
        const float inv_l = 1.0f / (lw + lcomb[qtile][lane]);
        const int token = b * 2048 + q0 + l31;
#pragma unroll
        for (int dt = 0; dt < 2; ++dt)
#pragma unroll
            for (int g = 0; g < 4; ++g) {
                const floatx4 v2 = comb[qtile][dt * 4 + g][lane];
                bf16_4 ok;
#pragma unroll
                for (int r4 = 0; r4 < 4; ++r4)
                    ok[r4] = (__bf16)((oacc[dt][g * 4 + r4] + v2[r4]) * inv_l);
                *(bf16_4*)&attn_ws[(size_t)token * 1024 + h * 64 + dt * 32 + g * 8 + hi * 4] = ok;
            }
    }
}

// ---------------------------------------------------------------------------
// Kernel 3: proj GEMM + bias -> f32 out. M=4096, N=1024, K=1024.
// 128x64 tiles, grid (16, 32) = 512 blocks. 2-phase double-buffered staging
// (48 KB LDS -> 2 blocks/CU resident): stage(k+1) -> compute(k) -> barrier.
// ---------------------------------------------------------------------------
__device__ __forceinline__ void proj_stage(
    const __bf16* __restrict__ A, const __bf16* __restrict__ Bp,
    int k0, __bf16* As, __bf16* Bs, int tid)
{
#pragma unroll
    for (int it = 0; it < 4; ++it) {               // A: 128 rows x 8 chunks
        int cc = it * 256 + tid;
        int row = cc >> 3, kc = cc & 7;
        gld16(A + row * 1024 + k0 + ((kc ^ (row & 7)) * 8), &As[cc * 8]);
    }
#pragma unroll
    for (int it = 0; it < 2; ++it) {               // B: 64 rows x 8 chunks
        int cc = it * 256 + tid;
        int row = cc >> 3, kc = cc & 7;
        gld16(Bp + row * 1024 + k0 + ((kc ^ (row & 7)) * 8), &Bs[cc * 8]);
    }
}

__global__ __launch_bounds__(256) void proj_gemm(
    const __bf16* __restrict__ Ain, const __bf16* __restrict__ W,
    const float* __restrict__ bias, float* __restrict__ out)
{
    __shared__ __align__(16) __bf16 As[2][128 * 64];   // [buf][m][k] swizzled
    __shared__ __align__(16) __bf16 Bs[2][64 * 64];    // [buf][n][k] swizzled
    floatx4 acc[4][2] = {};
    const int m0 = blockIdx.y * 128, n0 = blockIdx.x * 64;

    const int tid = threadIdx.x, lane = tid & 63, wv = tid >> 6;
    const int quad = lane >> 4, l15 = lane & 15;
    const int wm = (wv >> 1) * 64, wn = (wv & 1) * 32;

    const __bf16* A  = Ain + (size_t)m0 * 1024;
    const __bf16* Bp = W   + (size_t)n0 * 1024;

    proj_stage(A, Bp, 0, As[0], Bs[0], tid);
    __syncthreads();

#pragma unroll 2
    for (int kk = 0; kk < 16; ++kk) {
        const int cur = kk & 1;
        if (kk < 15)
            proj_stage(A, Bp, (kk + 1) * 64, As[cur ^ 1], Bs[cur ^ 1], tid);

        const __bf16* Ab = As[cur];
        const __bf16* Bb = Bs[cur];
#pragma unroll
        for (int ks = 0; ks < 2; ++ks) {
            bf16_8 af[4], bf[2];
#pragma unroll
            for (int mt = 0; mt < 4; ++mt) {
                int r = wm + mt * 16 + l15;
                af[mt] = *(const bf16_8*)&Ab[r * 64 + (((ks * 4 + quad) ^ (r & 7)) * 8)];
            }
#pragma unroll
            for (int nt = 0; nt < 2; ++nt) {
                int r = wn + nt * 16 + l15;
                bf[nt] = *(const bf16_8*)&Bb[r * 64 + (((ks * 4 + quad) ^ (r & 7)) * 8)];
            }
#pragma unroll
            for (int mt = 0; mt < 4; ++mt)
#pragma unroll
                for (int nt = 0; nt < 2; ++nt)
                    acc[mt][nt] = MFMA16(af[mt], bf[nt], acc[mt][nt], 0, 0, 0);
        }

        if (kk < 15) {
            __asm__ __volatile__("s_waitcnt vmcnt(0)" ::: "memory");
            __syncthreads();
        }
    }

    float bv[2];
#pragma unroll
    for (int nt = 0; nt < 2; ++nt) bv[nt] = bias[n0 + wn + nt * 16 + l15];

#pragma unroll
    for (int mt = 0; mt < 4; ++mt) {
        const int m = m0 + wm + mt * 16 + quad * 4;
#pragma unroll
        for (int nt = 0; nt < 2; ++nt) {
            const int n = n0 + wn + nt * 16 + l15;
#pragma unroll
            for (int r = 0; r < 4; ++r)
                out[(size_t)(m + r) * 1024 + n] = acc[mt][nt][r] + bv[nt];
        }
    }
}

// ---------------------------------------------------------------------------
extern "C" void kernel_launch(void* const* d_in, const int* in_sizes, int n_in,
                              void* d_out, int out_size, void* d_ws, size_t ws_size,
                              hipStream_t stream)
{
    const float* x      = (const float*)d_in[0];
    const float* qkv_w  = (const float*)d_in[2];
    const float* proj_w = (const float*)d_in[3];
    const float* proj_b = (const float*)d_in[4];
    float* out = (float*)d_out;

    const size_t SZ   = 4096 * 1024;
    const size_t WQKV = 3072 * 1024;
    const size_t WPRJ = 1024 * 1024;

    __bf16* xb      = (__bf16*)d_ws;
    __bf16* qkvwb   = xb + SZ;
    __bf16* projwb  = qkvwb + WQKV;
    __bf16* q_ws    = projwb + WPRJ;
    __bf16* k_ws    = q_ws + SZ;
    __bf16* vt_ws   = k_ws + SZ;
    __bf16* attn_ws = vt_ws + SZ;

    cvt_all<<<dim3(8192), 256, 0, stream>>>(x, qkv_w, proj_w, xb, qkvwb, projwb);
    qkv_gemm  <<<dim3(24, 32), 256, 0, stream>>>(xb, qkvwb, q_ws, k_ws, vt_ws);
    attn_kernel<<<dim3(32, 32), 256, 0, stream>>>(q_ws, k_ws, vt_ws, attn_ws);
    proj_gemm <<<dim3(16, 32), 256, 0, stream>>>(attn_ws, projwb, proj_b, out);
}

// Round 9
// 183.416 us; speedup vs baseline: 1.0068x; 1.0068x over previous
//
#include <hip/hip_runtime.h>

// ---------------------------------------------------------------------------
// Attention_52424370815683: B=2, S=2048, D=1024, H=16, hd=64. f32 I/O.
//   k0: convert x|qkv_w|proj_w f32 -> bf16 (single merged launch)
//   k1: qkv GEMM, 128x128 BK=64 dbuf 2-phase, **512 thr / 8 waves (2Mx4N)**
//       -> 4 waves/SIMD (was 2: barrier-drain exposed). q[b,h,s,d], k/v
//       written PRE-FRAGMENTED for attn MFMA32 (k pre-scaled by CSCALE).
//   k2: flash attention: r6 version VERBATIM (r7/r8's QK/exp interleave
//       failed correctness twice with an unlocated race -> abandoned).
//       reg-frag K/V, in-block split-K, XCD remap, fzero C-in, cvt_pk,
//       packed lsum. 54.5 us, register-capped 2 waves/SIMD.
//   k3: out(f32) = attn @ proj_w^T + proj_b, 128x64 tiles, 2-phase dbuf.
//
// Pre-fragmented K layout (elements, per bh):  ((kt*2 + t)*2048) + s*512
//   + lane*8, lane = hi*32+l31 holds K[key=kt*64+t*32+l31][d=s*16+hi*8..+7].
// Pre-fragmented V layout: ((kt*2 + dt)*2048) + s*512 + lane*8, lane holds
//   Vt[d=dt*32+l31][key=kt*64+s*16+hi*8..+7].  8KB per kt tile each.
// ---------------------------------------------------------------------------

typedef __bf16 bf16_8 __attribute__((ext_vector_type(8)));
typedef __bf16 bf16_4 __attribute__((ext_vector_type(4)));
typedef __bf16 bf16_2 __attribute__((ext_vector_type(2)));
typedef float floatx2 __attribute__((ext_vector_type(2)));
typedef float floatx4 __attribute__((ext_vector_type(4)));
typedef float floatx16 __attribute__((ext_vector_type(16)));
typedef unsigned uintx4 __attribute__((ext_vector_type(4)));

#define MFMA16 __builtin_amdgcn_mfma_f32_16x16x32_bf16
#define MFMA32 __builtin_amdgcn_mfma_f32_32x32x16_bf16
#define CSCALE 0.1803368801111204f   // hd^-0.5 * log2(e)
#define EXP2R  __builtin_amdgcn_exp2f   // bare v_exp_f32 (no OCML denorm fixup)

__device__ __forceinline__ void gld16(const __bf16* g, __bf16* l) {
    __builtin_amdgcn_global_load_lds(
        (const __attribute__((address_space(1))) void*)g,
        (__attribute__((address_space(3))) void*)l, 16, 0, 0);
}

// single-instruction packed f32->bf16 (RNE), lo = a, hi = b
__device__ __forceinline__ unsigned cvtpk_bf16(float a, float b) {
    unsigned d;
    __asm__("v_cvt_pk_bf16_f32 %0, %1, %2" : "=v"(d) : "v"(a), "v"(b));
    return d;
}

// v_permlane32_swap_b32: after the op, a = {a_lo, b_lo}, b = {a_hi, b_hi}
// volatile: exact r6 form (passing); keeps the swap pinned in program order.
__device__ __forceinline__ void pl32swap(unsigned& a, unsigned& b) {
    __asm__ __volatile__("v_permlane32_swap_b32 %0, %1" : "+v"(a), "+v"(b));
}

// ---------------------------------------------------------------------------
// Kernel 0: merged f32 -> bf16 convert for x (1M f4), qkv_w (768K), proj_w
// (256K). Grid exactly 2M float4s / 256.
// ---------------------------------------------------------------------------
__global__ __launch_bounds__(256) void cvt_all(
    const float* __restrict__ x, const float* __restrict__ w1,
    const float* __restrict__ w2,
    __bf16* __restrict__ xb, __bf16* __restrict__ w1b, __bf16* __restrict__ w2b)
{
    const int i = blockIdx.x * 256 + threadIdx.x;     // float4 index
    const float* src; __bf16* dst; int off;
    if (i < (1 << 20))                  { src = x;  dst = xb;  off = i; }
    else if (i < (1 << 20) + 786432)    { src = w1; dst = w1b; off = i - (1 << 20); }
    else                                { src = w2; dst = w2b; off = i - (1 << 20) - 786432; }
    float4 v = ((const float4*)src)[off];
    bf16_4 o;
    o[0] = (__bf16)v.x; o[1] = (__bf16)v.y; o[2] = (__bf16)v.z; o[3] = (__bf16)v.w;
    ((bf16_4*)dst)[off] = o;
}

// ---------------------------------------------------------------------------
// Kernel 1: QKV GEMM. M=4096, N=3072, K=1024. grid (24,32), 512 threads,
// 8 waves (2M x 4N), 128x128 tile, BK=64, double-buffered LDS (64 KB ->
// 2 blocks/CU = 16 waves/CU = 4 waves/SIMD). 2-phase: stage(k+1) ->
// compute(k) -> vmcnt(0)+barrier. q/k blocks (c<2): swapped operands ->
// feature-contiguous packed stores. k/v epilogues write pre-frag layouts.
// ---------------------------------------------------------------------------
__global__ __launch_bounds__(512) void qkv_gemm(
    const __bf16* __restrict__ X, const __bf16* __restrict__ W,
    __bf16* __restrict__ q_ws, __bf16* __restrict__ k_ws, __bf16* __restrict__ vt_ws)
{
    __shared__ __align__(16) __bf16 S[2][2][128 * 64];  // [buf][A/B] 64 KB

    const int tid = threadIdx.x, lane = tid & 63, wv = tid >> 6;   // wv 0..7
    const int quad = lane >> 4, l15 = lane & 15;
    const int wm = (wv >> 2) * 64, wn = (wv & 3) * 32;  // 2 x 4 wave grid
    const int m0 = blockIdx.y * 128, n0 = blockIdx.x * 128;
    const int c = n0 >> 10;                         // 0=q 1=k 2=v (block-uniform)

    // A/B row bases (both K-major, stride 1024). c<2: swapped (rows=feature).
    const __bf16* Abase;
    const __bf16* Bbase;
    if (c == 2) { Abase = X + (size_t)m0 * 1024; Bbase = W + (size_t)n0 * 1024; }
    else        { Abase = W + (size_t)n0 * 1024; Bbase = X + (size_t)m0 * 1024; }

    const int srow = tid >> 3, skc = tid & 7;       // srow 0..63, loop-invariant
    const int ssw  = (skc ^ (srow & 7)) * 8;

#define QKV_STAGE(buf, k0)                                                     \
    {                                                                          \
        _Pragma("unroll")                                                      \
        for (int itg = 0; itg < 2; ++itg) {                                    \
            const int cc = itg * 512 + tid;                                    \
            const int row = srow + itg * 64;                                   \
            gld16(Abase + row * 1024 + (k0) + ssw, &S[buf][0][cc * 8]);        \
            gld16(Bbase + row * 1024 + (k0) + ssw, &S[buf][1][cc * 8]);        \
        }                                                                      \
    }

    floatx4 acc[4][2] = {};
    QKV_STAGE(0, 0)
    __syncthreads();

#pragma unroll 1
    for (int kk = 0; kk < 16; ++kk) {
        const int cur = kk & 1;
        if (kk < 15) QKV_STAGE(cur ^ 1, (kk + 1) * 64)

        const __bf16* As = S[cur][0];
        const __bf16* Bs = S[cur][1];
#pragma unroll
        for (int ks = 0; ks < 2; ++ks) {
            bf16_8 af[4], bf[2];
#pragma unroll
            for (int mt = 0; mt < 4; ++mt) {
                int r = wm + mt * 16 + l15;
                af[mt] = *(const bf16_8*)&As[r * 64 + (((ks * 4 + quad) ^ (r & 7)) * 8)];
            }
#pragma unroll
            for (int nt = 0; nt < 2; ++nt) {
                int r = wn + nt * 16 + l15;
                bf[nt] = *(const bf16_8*)&Bs[r * 64 + (((ks * 4 + quad) ^ (r & 7)) * 8)];
            }
#pragma unroll
            for (int mt = 0; mt < 4; ++mt)
#pragma unroll
                for (int nt = 0; nt < 2; ++nt)
                    acc[mt][nt] = MFMA16(af[mt], bf[nt], acc[mt][nt], 0, 0, 0);
        }

        if (kk < 15) {
            __asm__ __volatile__("s_waitcnt vmcnt(0)" ::: "memory");
            __syncthreads();
        }
    }

    if (c == 2) {
        // V: D rows = token(key), cols = feature. Pack 4 consecutive keys.
#pragma unroll
        for (int mt = 0; mt < 4; ++mt) {
            const int mbase = m0 + wm + mt * 16 + quad * 4;   // token, 4-aligned
            const int b = mbase >> 11, key0 = mbase & 2047;
#pragma unroll
            for (int nt = 0; nt < 2; ++nt) {
                const int n = n0 + wn + nt * 16 + l15;
                const int h = (n >> 6) & 15, d = n & 63;
                const int dt = d >> 5, l31v = d & 31;
                bf16_4 pk;
#pragma unroll
                for (int r = 0; r < 4; ++r) pk[r] = (__bf16)acc[mt][nt][r];
                const size_t off =
                    (((size_t)(b * 16 + h) * 32 + (key0 >> 6)) * 2 + dt) * 2048
                    + ((key0 >> 4) & 3) * 512
                    + (((key0 >> 3) & 1) * 32 + l31v) * 8 + (key0 & 7);
                *(bf16_4*)&vt_ws[off] = pk;
            }
        }
    } else {
        const float scale = (c == 1) ? CSCALE : 1.0f;
#pragma unroll
        for (int mt = 0; mt < 4; ++mt) {
            const int nn = n0 + wm + mt * 16 + quad * 4;      // feature, 4-aligned
            const int h = (nn >> 6) & 15, d0 = nn & 63;
#pragma unroll
            for (int nt = 0; nt < 2; ++nt) {
                const int token = m0 + wn + nt * 16 + l15;
                const int b = token >> 11, key = token & 2047;
                bf16_4 pk;
#pragma unroll
                for (int r = 0; r < 4; ++r) pk[r] = (__bf16)(acc[mt][nt][r] * scale);
                if (c == 0) {
                    *(bf16_4*)&q_ws[((size_t)(b * 16 + h) * 2048 + key) * 64 + d0] = pk;
                } else {
                    const size_t off =
                        (((size_t)(b * 16 + h) * 32 + (key >> 6)) * 2 + ((key >> 5) & 1)) * 2048
                        + (d0 >> 4) * 512
                        + (((d0 >> 3) & 1) * 32 + (key & 31)) * 8 + (d0 & 7);
                    *(bf16_4*)&k_ws[off] = pk;
                }
            }
        }
    }
#undef QKV_STAGE
}

// ---------------------------------------------------------------------------
// Kernel 2: flash attention (r6 version, verbatim). reg-frag K/V, in-block
// split-K. grid (32,32) = 1024 blocks x 4 waves; register-capped 2
// waves/SIMD. Wave (qtile=w&1, keyhalf=w>>1): 32 q x 1024 keys (16 tiles).
// No main-loop barriers; one __syncthreads + f32 LDS merge (no-max softmax).
// XCD remap: linear%8 owns 4 bh -> L2-resident K/V (FETCH == unique 12 MB).
// VALU diet: fzero C-in, v_cvt_pk_bf16_f32 asm, packed f32x2 lsum.
// ---------------------------------------------------------------------------
__global__ __launch_bounds__(256) void attn_kernel(
    const __bf16* __restrict__ q_ws, const __bf16* __restrict__ k_ws,
    const __bf16* __restrict__ vt_ws, __bf16* __restrict__ attn_ws)
{
    __shared__ __align__(16) floatx4 comb[2][8][64];    // [qtile][j][lane] 16 KB
    __shared__ float lcomb[2][64];

    const int tid = threadIdx.x, lane = tid & 63, w = tid >> 6;   // w 0..3
    const int l31 = lane & 31, hi = lane >> 5;
    const int qtile = w & 1, keyhalf = w >> 1;

    // XCD-aware remap: linear % 8 = XCD; each XCD owns bh in [4x, 4x+4).
    const int linear = blockIdx.x + (blockIdx.y << 5);
    const int r = linear >> 3;
    const int bh = ((linear & 7) << 2) + (r & 3);
    const int qblk = r >> 2;                            // 0..31
    const int q0 = qblk * 64 + qtile * 32;

    const __bf16* __restrict__ qp  = q_ws  + (size_t)bh * (2048 * 64);
    const __bf16* __restrict__ kb0 = k_ws  + (size_t)bh * 131072 + keyhalf * 65536;
    const __bf16* __restrict__ kb1 = kb0 + 2048;
    const __bf16* __restrict__ vb0 = vt_ws + (size_t)bh * 131072 + keyhalf * 65536;
    const __bf16* __restrict__ vb1 = vb0 + 2048;

    const int vo = lane * 8;                // per-lane element offset (32-bit)

    // Q B-frags (4 k-steps of 16), held in registers all loop
    bf16_8 qf[4];
    {
        const int qrow = q0 + l31;
#pragma unroll
        for (int s = 0; s < 4; ++s)
            qf[s] = *(const bf16_8*)&qp[qrow * 64 + s * 16 + hi * 8];
    }

    floatx16 oacc[2] = {};                  // [d-tile] O^T accumulators
    floatx2 ls2[4] = {};                    // packed row-sum partials
    const floatx16 fzero = {};              // persistent zero C-in (hoisted)

    bf16_8 ka[8], kb[8], va[8];
#pragma unroll
    for (int u = 0; u < 8; ++u)             // prologue: K tile 0 of this half
        ka[u] = *(const bf16_8*)&(u < 4 ? kb0 : kb1)[vo + (u & 3) * 512];

    // One 64-key tile. KC = current K frags, KN = prefetch target.
    // (Final prefetch reads 8KB past this wave's K half -> other half /
    //  next bh's K / vt_ws, all allocated; value never consumed.)
#define ATTN_TILE(KC, KN, KT)                                                  \
    {                                                                          \
        const int ko  = (KT) * 4096 + vo;                                      \
        const int kon = ko + 4096;                                             \
        _Pragma("unroll")                                                      \
        for (int u = 0; u < 8; ++u)   /* V(t): covered by QK+exp phases */     \
            va[u] = *(const bf16_8*)&(u < 4 ? vb0 : vb1)[ko + (u & 3) * 512];  \
        floatx16 sacc[2];                                                      \
        __builtin_amdgcn_s_setprio(1);                                         \
        sacc[0] = MFMA32(KC[0], qf[0], fzero, 0, 0, 0);                        \
        sacc[1] = MFMA32(KC[4], qf[0], fzero, 0, 0, 0);                        \
        _Pragma("unroll")                                                      \
        for (int s = 1; s < 4; ++s) {                                          \
            sacc[0] = MFMA32(KC[s],     qf[s], sacc[0], 0, 0, 0);              \
            sacc[1] = MFMA32(KC[4 + s], qf[s], sacc[1], 0, 0, 0);              \
        }                                                                      \
        __builtin_amdgcn_s_setprio(0);                                         \
        _Pragma("unroll")                                                      \
        for (int u = 0; u < 8; ++u)   /* K(t+1) prefetch */                    \
            KN[u] = *(const bf16_8*)&(u < 4 ? kb0 : kb1)[kon + (u & 3) * 512]; \
        unsigned D[2][4][2];                                                   \
        _Pragma("unroll")                                                      \
        for (int t = 0; t < 2; ++t)                                            \
            _Pragma("unroll")                                                  \
            for (int j = 0; j < 4; ++j)                                        \
                _Pragma("unroll")                                              \
                for (int e = 0; e < 2; ++e) {                                  \
                    float pa = EXP2R(sacc[t][j * 4 + e * 2]);                  \
                    float pb = EXP2R(sacc[t][j * 4 + e * 2 + 1]);              \
                    floatx2 p2; p2[0] = pa; p2[1] = pb;                        \
                    ls2[t * 2 + e] += p2;        /* v_pk_add_f32 */            \
                    D[t][j][e] = cvtpk_bf16(pa, pb);                           \
                }                                                              \
        __builtin_amdgcn_s_setprio(1);                                         \
        _Pragma("unroll")                                                      \
        for (int s = 0; s < 4; ++s) {                                          \
            const int t = s >> 1, b2 = (s & 1) * 2;                            \
            unsigned x0 = D[t][b2][0], y0 = D[t][b2 + 1][0];                   \
            unsigned x1 = D[t][b2][1], y1 = D[t][b2 + 1][1];                   \
            pl32swap(x0, y0);                                                  \
            pl32swap(x1, y1);                                                  \
            uintx4 uu; uu[0] = x0; uu[1] = x1; uu[2] = y0; uu[3] = y1;         \
            const bf16_8 pf = __builtin_bit_cast(bf16_8, uu);                  \
            oacc[0] = MFMA32(va[s],     pf, oacc[0], 0, 0, 0);                 \
            oacc[1] = MFMA32(va[4 + s], pf, oacc[1], 0, 0, 0);                 \
        }                                                                      \
        __builtin_amdgcn_s_setprio(0);                                         \
    }

#pragma unroll 1
    for (int it = 0; it < 8; ++it) {
        ATTN_TILE(ka, kb, (it * 2))
        ATTN_TILE(kb, ka, (it * 2 + 1))
    }
#undef ATTN_TILE

    // ---- this wave's row-sums over its 1024 keys (combine hi halves)
    const floatx2 lv = (ls2[0] + ls2[1]) + (ls2[2] + ls2[3]);
    const float lsum = lv[0] + lv[1];
    const float lw = lsum + __shfl_xor(lsum, 32, 64);

    // ---- split-K merge: keyhalf=1 waves dump f32 O + l to LDS; keyhalf=0
    // waves add, normalize, store. Lane-aligned (same q<->lane mapping).
    if (keyhalf == 1) {
#pragma unroll
        for (int dt = 0; dt < 2; ++dt)
#pragma unroll
            for (int g = 0; g < 4; ++g) {
                floatx4 v4;
#pragma unroll
                for (int r4 = 0; r4 < 4; ++r4) v4[r4] = oacc[dt][g * 4 + r4];
                comb[qtile][dt * 4 + g][lane] = v4;
            }
        lcomb[qtile][lane] = lw;
    }
    __syncthreads();
    if (keyhalf == 0) {
        // oacc C32 layout: col = q = lane&31, row d = (r&3)+8*(r>>2)+4*hi.
        const int b = bh >> 4, h = bh & 15;
        const float inv_l = 1.0f / (lw + lcomb[qtile][lane]);
        const int token = b * 2048 + q0 + l31;
#pragma unroll
        for (int dt = 0; dt < 2; ++dt)
#pragma unroll
            for (int g = 0; g < 4; ++g) {
                const floatx4 v2 = comb[qtile][dt * 4 + g][lane];
                bf16_4 ok;
#pragma unroll
                for (int r4 = 0; r4 < 4; ++r4)
                    ok[r4] = (__bf16)((oacc[dt][g * 4 + r4] + v2[r4]) * inv_l);
                *(bf16_4*)&attn_ws[(size_t)token * 1024 + h * 64 + dt * 32 + g * 8 + hi * 4] = ok;
            }
    }
}

// ---------------------------------------------------------------------------
// Kernel 3: proj GEMM + bias -> f32 out. M=4096, N=1024, K=1024.
// 128x64 tiles, grid (16, 32) = 512 blocks. 2-phase double-buffered staging
// (48 KB LDS -> 2 blocks/CU resident): stage(k+1) -> compute(k) -> barrier.
// ---------------------------------------------------------------------------
__device__ __forceinline__ void proj_stage(
    const __bf16* __restrict__ A, const __bf16* __restrict__ Bp,
    int k0, __bf16* As, __bf16* Bs, int tid)
{
#pragma unroll
    for (int it = 0; it < 4; ++it) {               // A: 128 rows x 8 chunks
        int cc = it * 256 + tid;
        int row = cc >> 3, kc = cc & 7;
        gld16(A + row * 1024 + k0 + ((kc ^ (row & 7)) * 8), &As[cc * 8]);
    }
#pragma unroll
    for (int it = 0; it < 2; ++it) {               // B: 64 rows x 8 chunks
        int cc = it * 256 + tid;
        int row = cc >> 3, kc = cc & 7;
        gld16(Bp + row * 1024 + k0 + ((kc ^ (row & 7)) * 8), &Bs[cc * 8]);
    }
}

__global__ __launch_bounds__(256) void proj_gemm(
    const __bf16* __restrict__ Ain, const __bf16* __restrict__ W,
    const float* __restrict__ bias, float* __restrict__ out)
{
    __shared__ __align__(16) __bf16 As[2][128 * 64];   // [buf][m][k] swizzled
    __shared__ __align__(16) __bf16 Bs[2][64 * 64];    // [buf][n][k] swizzled
    floatx4 acc[4][2] = {};
    const int m0 = blockIdx.y * 128, n0 = blockIdx.x * 64;

    const int tid = threadIdx.x, lane = tid & 63, wv = tid >> 6;
    const int quad = lane >> 4, l15 = lane & 15;
    const int wm = (wv >> 1) * 64, wn = (wv & 1) * 32;

    const __bf16* A  = Ain + (size_t)m0 * 1024;
    const __bf16* Bp = W   + (size_t)n0 * 1024;

    proj_stage(A, Bp, 0, As[0], Bs[0], tid);
    __syncthreads();

#pragma unroll 2
    for (int kk = 0; kk < 16; ++kk) {
        const int cur = kk & 1;
        if (kk < 15)
            proj_stage(A, Bp, (kk + 1) * 64, As[cur ^ 1], Bs[cur ^ 1], tid);

        const __bf16* Ab = As[cur];
        const __bf16* Bb = Bs[cur];
#pragma unroll
        for (int ks = 0; ks < 2; ++ks) {
            bf16_8 af[4], bf[2];
#pragma unroll
            for (int mt = 0; mt < 4; ++mt) {
                int r = wm + mt * 16 + l15;
                af[mt] = *(const bf16_8*)&Ab[r * 64 + (((ks * 4 + quad) ^ (r & 7)) * 8)];
            }
#pragma unroll
            for (int nt = 0; nt < 2; ++nt) {
                int r = wn + nt * 16 + l15;
                bf[nt] = *(const bf16_8*)&Bb[r * 64 + (((ks * 4 + quad) ^ (r & 7)) * 8)];
            }
#pragma unroll
            for (int mt = 0; mt < 4; ++mt)
#pragma unroll
                for (int nt = 0; nt < 2; ++nt)
                    acc[mt][nt] = MFMA16(af[mt], bf[nt], acc[mt][nt], 0, 0, 0);
        }

        if (kk < 15) {
            __asm__ __volatile__("s_waitcnt vmcnt(0)" ::: "memory");
            __syncthreads();
        }
    }

    float bv[2];
#pragma unroll
    for (int nt = 0; nt < 2; ++nt) bv[nt] = bias[n0 + wn + nt * 16 + l15];

#pragma unroll
    for (int mt = 0; mt < 4; ++mt) {
        const int m = m0 + wm + mt * 16 + quad * 4;
#pragma unroll
        for (int nt = 0; nt < 2; ++nt) {
            const int n = n0 + wn + nt * 16 + l15;
#pragma unroll
            for (int r = 0; r < 4; ++r)
                out[(size_t)(m + r) * 1024 + n] = acc[mt][nt][r] + bv[nt];
        }
    }
}

// ---------------------------------------------------------------------------
extern "C" void kernel_launch(void* const* d_in, const int* in_sizes, int n_in,
                              void* d_out, int out_size, void* d_ws, size_t ws_size,
                              hipStream_t stream)
{
    const float* x      = (const float*)d_in[0];
    const float* qkv_w  = (const float*)d_in[2];
    const float* proj_w = (const float*)d_in[3];
    const float* proj_b = (const float*)d_in[4];
    float* out = (float*)d_out;

    const size_t SZ   = 4096 * 1024;
    const size_t WQKV = 3072 * 1024;
    const size_t WPRJ = 1024 * 1024;

    __bf16* xb      = (__bf16*)d_ws;
    __bf16* qkvwb   = xb + SZ;
    __bf16* projwb  = qkvwb + WQKV;
    __bf16* q_ws    = projwb + WPRJ;
    __bf16* k_ws    = q_ws + SZ;
    __bf16* vt_ws   = k_ws + SZ;
    __bf16* attn_ws = vt_ws + SZ;

    cvt_all<<<dim3(8192), 256, 0, stream>>>(x, qkv_w, proj_w, xb, qkvwb, projwb);
    qkv_gemm  <<<dim3(24, 32), 512, 0, stream>>>(xb, qkvwb, q_ws, k_ws, vt_ws);
    attn_kernel<<<dim3(32, 32), 256, 0, stream>>>(q_ws, k_ws, vt_ws, attn_ws);
    proj_gemm <<<dim3(16, 32), 256, 0, stream>>>(attn_ws, projwb, proj_b, out);
}

// Round 10
// 177.518 us; speedup vs baseline: 1.0403x; 1.0332x over previous
//
#include <hip/hip_runtime.h>

// ---------------------------------------------------------------------------
// Attention_52424370815683: B=2, S=2048, D=1024, H=16, hd=64. f32 I/O.
//   k0: convert x|qkv_w|proj_w f32 -> bf16 (single merged launch)
//   k1: qkv GEMM, 128x128 BK=64 dbuf 2-phase, 512 thr / 8 waves (2Mx4N)
//       -> q[b,h,s,d], k[b,h,s,d] (pre-scaled by CSCALE), vT[b,h,d,s]
//   k2: flash attention, COMPOSED from proven pieces (r10):
//       r0's occupancy regime (512 thr, 64KB LDS dbuf, 2 blk/CU, 4 w/SIMD)
//       + r2's 32x32 swapped-QK with in-register P (cvt_pk + permlane swap)
//       + r9's split-K LDS merge. 8 waves = 4 qtiles x 2 keyhalves; each
//       wave 32q x 1024 keys from its half's LDS K/V. Fused per-s
//       exp->swap->PV (within-tile only -- no cross-tile pipeline state).
//   k3: out(f32) = attn @ proj_w^T + proj_b, 128x64 tiles, 2-phase dbuf.
// ---------------------------------------------------------------------------

typedef __bf16 bf16_8 __attribute__((ext_vector_type(8)));
typedef __bf16 bf16_4 __attribute__((ext_vector_type(4)));
typedef __bf16 bf16_2 __attribute__((ext_vector_type(2)));
typedef float floatx2 __attribute__((ext_vector_type(2)));
typedef float floatx4 __attribute__((ext_vector_type(4)));
typedef float floatx16 __attribute__((ext_vector_type(16)));
typedef unsigned uintx4 __attribute__((ext_vector_type(4)));

#define MFMA16 __builtin_amdgcn_mfma_f32_16x16x32_bf16
#define MFMA32 __builtin_amdgcn_mfma_f32_32x32x16_bf16
#define CSCALE 0.1803368801111204f   // hd^-0.5 * log2(e)
#define EXP2R  __builtin_amdgcn_exp2f   // bare v_exp_f32 (no OCML denorm fixup)

__device__ __forceinline__ void gld16(const __bf16* g, __bf16* l) {
    __builtin_amdgcn_global_load_lds(
        (const __attribute__((address_space(1))) void*)g,
        (__attribute__((address_space(3))) void*)l, 16, 0, 0);
}

// single-instruction packed f32->bf16 (RNE), lo = a, hi = b
__device__ __forceinline__ unsigned cvtpk_bf16(float a, float b) {
    unsigned d;
    __asm__("v_cvt_pk_bf16_f32 %0, %1, %2" : "=v"(d) : "v"(a), "v"(b));
    return d;
}

// v_permlane32_swap_b32: after the op, a = {a_lo, b_lo}, b = {a_hi, b_hi}
// volatile: the r2/r6 (passing) form -- pinned in program order.
__device__ __forceinline__ void pl32swap(unsigned& a, unsigned& b) {
    __asm__ __volatile__("v_permlane32_swap_b32 %0, %1" : "+v"(a), "+v"(b));
}

// ---------------------------------------------------------------------------
// Kernel 0: merged f32 -> bf16 convert for x (1M f4), qkv_w (768K), proj_w
// (256K). Grid exactly 2M float4s / 256.
// ---------------------------------------------------------------------------
__global__ __launch_bounds__(256) void cvt_all(
    const float* __restrict__ x, const float* __restrict__ w1,
    const float* __restrict__ w2,
    __bf16* __restrict__ xb, __bf16* __restrict__ w1b, __bf16* __restrict__ w2b)
{
    const int i = blockIdx.x * 256 + threadIdx.x;     // float4 index
    const float* src; __bf16* dst; int off;
    if (i < (1 << 20))                  { src = x;  dst = xb;  off = i; }
    else if (i < (1 << 20) + 786432)    { src = w1; dst = w1b; off = i - (1 << 20); }
    else                                { src = w2; dst = w2b; off = i - (1 << 20) - 786432; }
    float4 v = ((const float4*)src)[off];
    bf16_4 o;
    o[0] = (__bf16)v.x; o[1] = (__bf16)v.y; o[2] = (__bf16)v.z; o[3] = (__bf16)v.w;
    ((bf16_4*)dst)[off] = o;
}

// ---------------------------------------------------------------------------
// Kernel 1: QKV GEMM. M=4096, N=3072, K=1024. grid (24,32), 512 threads,
// 8 waves (2M x 4N), 128x128 tile, BK=64, double-buffered LDS (64 KB ->
// 2 blocks/CU = 4 waves/SIMD). 2-phase: stage(k+1) -> compute(k) ->
// vmcnt(0)+barrier. q/k blocks (c<2): swapped operands -> d-contiguous
// packed stores. Epilogues: q/k -> [b,h,s,d] (k scaled), v -> vT[b,h,d,s].
// ---------------------------------------------------------------------------
__global__ __launch_bounds__(512) void qkv_gemm(
    const __bf16* __restrict__ X, const __bf16* __restrict__ W,
    __bf16* __restrict__ q_ws, __bf16* __restrict__ k_ws, __bf16* __restrict__ vt_ws)
{
    __shared__ __align__(16) __bf16 S[2][2][128 * 64];  // [buf][A/B] 64 KB

    const int tid = threadIdx.x, lane = tid & 63, wv = tid >> 6;   // wv 0..7
    const int quad = lane >> 4, l15 = lane & 15;
    const int wm = (wv >> 2) * 64, wn = (wv & 3) * 32;  // 2 x 4 wave grid
    const int m0 = blockIdx.y * 128, n0 = blockIdx.x * 128;
    const int c = n0 >> 10;                         // 0=q 1=k 2=v (block-uniform)

    // A/B row bases (both K-major, stride 1024). c<2: swapped (rows=feature).
    const __bf16* Abase;
    const __bf16* Bbase;
    if (c == 2) { Abase = X + (size_t)m0 * 1024; Bbase = W + (size_t)n0 * 1024; }
    else        { Abase = W + (size_t)n0 * 1024; Bbase = X + (size_t)m0 * 1024; }

    const int srow = tid >> 3, skc = tid & 7;       // srow 0..63, loop-invariant
    const int ssw  = (skc ^ (srow & 7)) * 8;

#define QKV_STAGE(buf, k0)                                                     \
    {                                                                          \
        _Pragma("unroll")                                                      \
        for (int itg = 0; itg < 2; ++itg) {                                    \
            const int cc = itg * 512 + tid;                                    \
            const int row = srow + itg * 64;                                   \
            gld16(Abase + row * 1024 + (k0) + ssw, &S[buf][0][cc * 8]);        \
            gld16(Bbase + row * 1024 + (k0) + ssw, &S[buf][1][cc * 8]);        \
        }                                                                      \
    }

    floatx4 acc[4][2] = {};
    QKV_STAGE(0, 0)
    __syncthreads();

#pragma unroll 1
    for (int kk = 0; kk < 16; ++kk) {
        const int cur = kk & 1;
        if (kk < 15) QKV_STAGE(cur ^ 1, (kk + 1) * 64)

        const __bf16* As = S[cur][0];
        const __bf16* Bs = S[cur][1];
#pragma unroll
        for (int ks = 0; ks < 2; ++ks) {
            bf16_8 af[4], bf[2];
#pragma unroll
            for (int mt = 0; mt < 4; ++mt) {
                int r = wm + mt * 16 + l15;
                af[mt] = *(const bf16_8*)&As[r * 64 + (((ks * 4 + quad) ^ (r & 7)) * 8)];
            }
#pragma unroll
            for (int nt = 0; nt < 2; ++nt) {
                int r = wn + nt * 16 + l15;
                bf[nt] = *(const bf16_8*)&Bs[r * 64 + (((ks * 4 + quad) ^ (r & 7)) * 8)];
            }
#pragma unroll
            for (int mt = 0; mt < 4; ++mt)
#pragma unroll
                for (int nt = 0; nt < 2; ++nt)
                    acc[mt][nt] = MFMA16(af[mt], bf[nt], acc[mt][nt], 0, 0, 0);
        }

        if (kk < 15) {
            __asm__ __volatile__("s_waitcnt vmcnt(0)" ::: "memory");
            __syncthreads();
        }
    }

    if (c == 2) {
        // V: D rows = token, cols = feature. Pack 4 consecutive tokens -> vT.
#pragma unroll
        for (int mt = 0; mt < 4; ++mt) {
            const int mbase = m0 + wm + mt * 16 + quad * 4;   // token, 4-aligned
            const int b = mbase >> 11, s = mbase & 2047;
#pragma unroll
            for (int nt = 0; nt < 2; ++nt) {
                const int n = n0 + wn + nt * 16 + l15;
                const int h = (n >> 6) & 15, d = n & 63;
                bf16_4 pk;
#pragma unroll
                for (int r = 0; r < 4; ++r) pk[r] = (__bf16)acc[mt][nt][r];
                *(bf16_4*)&vt_ws[((size_t)(b * 16 + h) * 64 + d) * 2048 + s] = pk;
            }
        }
    } else {
        // q/k: swapped -> D rows = feature, cols = token. d-contiguous stores.
        __bf16* dst = (c == 0) ? q_ws : k_ws;
        const float scale = (c == 1) ? CSCALE : 1.0f;
#pragma unroll
        for (int mt = 0; mt < 4; ++mt) {
            const int nn = n0 + wm + mt * 16 + quad * 4;      // feature, 4-aligned
            const int h = (nn >> 6) & 15, d0 = nn & 63;
#pragma unroll
            for (int nt = 0; nt < 2; ++nt) {
                const int token = m0 + wn + nt * 16 + l15;
                const int b = token >> 11, skey = token & 2047;
                bf16_4 pk;
#pragma unroll
                for (int r = 0; r < 4; ++r) pk[r] = (__bf16)(acc[mt][nt][r] * scale);
                *(bf16_4*)&dst[((size_t)(b * 16 + h) * 2048 + skey) * 64 + d0] = pk;
            }
        }
    }
#undef QKV_STAGE
}

// ---------------------------------------------------------------------------
// Kernel 2: flash attention. grid (16 qt, 32 bh) remapped (linear%8 = XCD
// owns 4 bh -> ~3 MB L2 working set). 512 thr / 8 waves: qtile = w&3,
// keyhalf = w>>2. Each wave: 32 q x 1024 keys = 16 tiles of 64 keys from
// its half's double-buffered LDS K/V (staged by the half's 256 threads,
// shared by its 4 waves -> per-wave regs ~120 -> 4 waves/SIMD). Per tile:
// QK (8 MFMA32, fzero C-in) then fused per-s {exp/pack -> permlane swap ->
// 2 PV MFMA} -- all within-tile, sequential semantics (r2-proven math).
// Split-K merge: keyhalf=1 dumps f32 O+l into LDS overlay, keyhalf=0 adds,
// normalizes, stores (no-max softmax -> pure add).
// ---------------------------------------------------------------------------
__global__ __launch_bounds__(512, 4) void attn_kernel(
    const __bf16* __restrict__ q_ws, const __bf16* __restrict__ k_ws,
    const __bf16* __restrict__ vt_ws, __bf16* __restrict__ attn_ws)
{
    __shared__ __align__(16) __bf16 Ks [2][2][64 * 64];   // [half][buf] 32 KB
    __shared__ __align__(16) __bf16 Vts[2][2][64 * 64];   // [half][buf] 32 KB

    const int tid = threadIdx.x, lane = tid & 63, w = tid >> 6;   // w 0..7
    const int l31 = lane & 31, hi = lane >> 5;
    const int qtile = w & 3, keyhalf = w >> 2;
    const int htid = tid & 255;                     // thread within half

    // XCD remap: linear = bx + 16*by in [0,512); XCD = linear%8 owns 4 bh.
    const int linear = blockIdx.x + (blockIdx.y << 4);
    const int r = linear >> 3;                      // 0..63
    const int bh = ((linear & 7) << 2) + (r & 3);
    const int qt = r >> 2;                          // 0..15
    const int q0 = qt * 128 + qtile * 32;

    const __bf16* __restrict__ qp  = q_ws  + (size_t)bh * (2048 * 64);
    const __bf16* __restrict__ kp  = k_ws  + (size_t)bh * (2048 * 64);
    const __bf16* __restrict__ vtp = vt_ws + (size_t)bh * (64 * 2048);
    const int koff = keyhalf * 1024;                // this half's key base

    // staging: loop-invariant per-lane bases (r2 pattern, + keyhalf)
    const int srow = htid >> 3, skc = htid & 7;     // srow 0..31
    const int sw   = (skc ^ (srow & 7)) * 8;
    const __bf16* kb0 = kp  + (size_t)(koff + srow) * 64 + sw;
    const __bf16* kb1 = kp  + (size_t)(koff + srow + 32) * 64 + sw;
    const __bf16* vb0 = vtp + (size_t)srow * 2048 + koff + sw;
    const __bf16* vb1 = vtp + (size_t)(srow + 32) * 2048 + koff + sw;
    const int ldsoff = htid * 8;                    // wave-uniform + lane*16B

    // Q B-frags (4 k-steps of 16), held in registers all loop
    bf16_8 qf[4];
    {
        const int qrow = q0 + l31;
#pragma unroll
        for (int s = 0; s < 4; ++s)
            qf[s] = *(const bf16_8*)&qp[qrow * 64 + s * 16 + hi * 8];
    }

    floatx16 oacc[2] = {};                  // [d-tile] O^T accumulators
    floatx2 ls2[4] = {};                    // packed row-sum partials
    const floatx16 fzero = {};              // persistent zero C-in (hoisted)

    // prologue: stage tile 0 into buf 0
    gld16(kb0, &Ks [keyhalf][0][ldsoff]);
    gld16(kb1, &Ks [keyhalf][0][ldsoff + 2048]);
    gld16(vb0, &Vts[keyhalf][0][ldsoff]);
    gld16(vb1, &Vts[keyhalf][0][ldsoff + 2048]);
    __syncthreads();                        // drains vmcnt(0): buf0 ready

#pragma unroll 1
    for (int kt = 0; kt < 16; ++kt) {
        const int cur = kt & 1;
        // ---- issue next tile's stage FIRST (hidden under compute)
        if (kt < 15) {
            const int ko = (kt + 1) * 64;
            gld16(kb0 + ko * 64, &Ks [keyhalf][cur ^ 1][ldsoff]);
            gld16(kb1 + ko * 64, &Ks [keyhalf][cur ^ 1][ldsoff + 2048]);
            gld16(vb0 + ko,      &Vts[keyhalf][cur ^ 1][ldsoff]);
            gld16(vb1 + ko,      &Vts[keyhalf][cur ^ 1][ldsoff + 2048]);
        }
        const __bf16* Kb = Ks [keyhalf][cur];
        const __bf16* Vb = Vts[keyhalf][cur];

        // ---- S^T[64 key][32 q]: 2 key-subtiles x 4 k-steps
        floatx16 sacc[2];
        __builtin_amdgcn_s_setprio(1);
        {
            const int kc0 = hi;
            const int r0 = l31, r1 = 32 + l31;
            bf16_8 kf0 = *(const bf16_8*)&Kb[r0 * 64 + ((kc0 ^ (r0 & 7)) * 8)];
            bf16_8 kf1 = *(const bf16_8*)&Kb[r1 * 64 + ((kc0 ^ (r1 & 7)) * 8)];
            sacc[0] = MFMA32(kf0, qf[0], fzero, 0, 0, 0);
            sacc[1] = MFMA32(kf1, qf[0], fzero, 0, 0, 0);
        }
#pragma unroll
        for (int s = 1; s < 4; ++s) {
            const int kc = s * 2 + hi;
#pragma unroll
            for (int t = 0; t < 2; ++t) {
                const int row = t * 32 + l31;
                bf16_8 kf = *(const bf16_8*)&Kb[row * 64 + ((kc ^ (row & 7)) * 8)];
                sacc[t] = MFMA32(kf, qf[s], sacc[t], 0, 0, 0);
            }
        }
        __builtin_amdgcn_s_setprio(0);

        // ---- fused per-s: exp/pack quarter -> permlane swap -> 2 PV MFMAs
        // (r2's math, reordered within the tile; D live = 4 regs)
#pragma unroll
        for (int s = 0; s < 4; ++s) {
            const int t = s >> 1, b2 = (s & 1) * 2;
            unsigned Dw[4];                 // [jrel*2+e], j = b2+jrel
#pragma unroll
            for (int jr = 0; jr < 2; ++jr)
#pragma unroll
                for (int e = 0; e < 2; ++e) {
                    const int j = b2 + jr;
                    float pa = EXP2R(sacc[t][j * 4 + e * 2]);
                    float pb = EXP2R(sacc[t][j * 4 + e * 2 + 1]);
                    floatx2 p2; p2[0] = pa; p2[1] = pb;
                    ls2[t * 2 + e] += p2;        // v_pk_add_f32
                    Dw[jr * 2 + e] = cvtpk_bf16(pa, pb);
                }
            unsigned x0 = Dw[0], y0 = Dw[2];     // D[t][b2][0], D[t][b2+1][0]
            unsigned x1 = Dw[1], y1 = Dw[3];     // D[t][b2][1], D[t][b2+1][1]
            pl32swap(x0, y0);
            pl32swap(x1, y1);
            uintx4 uu; uu[0] = x0; uu[1] = x1; uu[2] = y0; uu[3] = y1;
            const bf16_8 pf = __builtin_bit_cast(bf16_8, uu);
            const int kc = s * 2 + hi;
            __builtin_amdgcn_s_setprio(1);
#pragma unroll
            for (int dt = 0; dt < 2; ++dt) {
                const int drow = dt * 32 + l31;
                bf16_8 vf = *(const bf16_8*)&Vb[drow * 64 + ((kc ^ (drow & 7)) * 8)];
                oacc[dt] = MFMA32(vf, pf, oacc[dt], 0, 0, 0);
            }
            __builtin_amdgcn_s_setprio(0);
        }

        // ---- single barrier per tile: stage loads drained + buf reads done
        if (kt < 15) {
            __asm__ __volatile__("s_waitcnt vmcnt(0)" ::: "memory");
            __syncthreads();
        }
    }

    // ---- this wave's row-sums over its 1024 keys (combine hi halves)
    const floatx2 lv = (ls2[0] + ls2[1]) + (ls2[2] + ls2[3]);
    const float lsum = lv[0] + lv[1];
    const float lw = lsum + __shfl_xor(lsum, 32, 64);

    // ---- split-K merge (LDS overlay on K/V buffers; all reads done)
    __syncthreads();
    floatx4* comb  = (floatx4*)&Ks[0][0][0];    // [qtile][8][64] = 32 KB exact
    float*   lcomb = (float*)&Vts[0][0][0];     // [qtile][64] = 1 KB

    if (keyhalf == 1) {
#pragma unroll
        for (int dt = 0; dt < 2; ++dt)
#pragma unroll
            for (int g = 0; g < 4; ++g) {
                floatx4 v4;
#pragma unroll
                for (int r4 = 0; r4 < 4; ++r4) v4[r4] = oacc[dt][g * 4 + r4];
                comb[((qtile * 8 + dt * 4 + g) << 6) + lane] = v4;
            }
        lcomb[(qtile << 6) + lane] = lw;
    }
    __syncthreads();
    if (keyhalf == 0) {
        // oacc C32 layout: col = q = lane&31, row d = (r&3)+8*(r>>2)+4*hi.
        const int b = bh >> 4, h = bh & 15;
        const float inv_l = 1.0f / (lw + lcomb[(qtile << 6) + lane]);
        const int token = b * 2048 + q0 + l31;
#pragma unroll
        for (int dt = 0; dt < 2; ++dt)
#pragma unroll
            for (int g = 0; g < 4; ++g) {
                const floatx4 v2 = comb[((qtile * 8 + dt * 4 + g) << 6) + lane];
                bf16_4 ok;
#pragma unroll
                for (int r4 = 0; r4 < 4; ++r4)
                    ok[r4] = (__bf16)((oacc[dt][g * 4 + r4] + v2[r4]) * inv_l);
                *(bf16_4*)&attn_ws[(size_t)token * 1024 + h * 64 + dt * 32 + g * 8 + hi * 4] = ok;
            }
    }
}

// ---------------------------------------------------------------------------
// Kernel 3: proj GEMM + bias -> f32 out. M=4096, N=1024, K=1024.
// 128x64 tiles, grid (16, 32) = 512 blocks. 2-phase double-buffered staging
// (48 KB LDS -> 2 blocks/CU resident): stage(k+1) -> compute(k) -> barrier.
// ---------------------------------------------------------------------------
__device__ __forceinline__ void proj_stage(
    const __bf16* __restrict__ A, const __bf16* __restrict__ Bp,
    int k0, __bf16* As, __bf16* Bs, int tid)
{
#pragma unroll
    for (int it = 0; it < 4; ++it) {               // A: 128 rows x 8 chunks
        int cc = it * 256 + tid;
        int row = cc >> 3, kc = cc & 7;
        gld16(A + row * 1024 + k0 + ((kc ^ (row & 7)) * 8), &As[cc * 8]);
    }
#pragma unroll
    for (int it = 0; it < 2; ++it) {               // B: 64 rows x 8 chunks
        int cc = it * 256 + tid;
        int row = cc >> 3, kc = cc & 7;
        gld16(Bp + row * 1024 + k0 + ((kc ^ (row & 7)) * 8), &Bs[cc * 8]);
    }
}

__global__ __launch_bounds__(256) void proj_gemm(
    const __bf16* __restrict__ Ain, const __bf16* __restrict__ W,
    const float* __restrict__ bias, float* __restrict__ out)
{
    __shared__ __align__(16) __bf16 As[2][128 * 64];   // [buf][m][k] swizzled
    __shared__ __align__(16) __bf16 Bs[2][64 * 64];    // [buf][n][k] swizzled
    floatx4 acc[4][2] = {};
    const int m0 = blockIdx.y * 128, n0 = blockIdx.x * 64;

    const int tid = threadIdx.x, lane = tid & 63, wv = tid >> 6;
    const int quad = lane >> 4, l15 = lane & 15;
    const int wm = (wv >> 1) * 64, wn = (wv & 1) * 32;

    const __bf16* A  = Ain + (size_t)m0 * 1024;
    const __bf16* Bp = W   + (size_t)n0 * 1024;

    proj_stage(A, Bp, 0, As[0], Bs[0], tid);
    __syncthreads();

#pragma unroll 2
    for (int kk = 0; kk < 16; ++kk) {
        const int cur = kk & 1;
        if (kk < 15)
            proj_stage(A, Bp, (kk + 1) * 64, As[cur ^ 1], Bs[cur ^ 1], tid);

        const __bf16* Ab = As[cur];
        const __bf16* Bb = Bs[cur];
#pragma unroll
        for (int ks = 0; ks < 2; ++ks) {
            bf16_8 af[4], bf[2];
#pragma unroll
            for (int mt = 0; mt < 4; ++mt) {
                int r = wm + mt * 16 + l15;
                af[mt] = *(const bf16_8*)&Ab[r * 64 + (((ks * 4 + quad) ^ (r & 7)) * 8)];
            }
#pragma unroll
            for (int nt = 0; nt < 2; ++nt) {
                int r = wn + nt * 16 + l15;
                bf[nt] = *(const bf16_8*)&Bb[r * 64 + (((ks * 4 + quad) ^ (r & 7)) * 8)];
            }
#pragma unroll
            for (int mt = 0; mt < 4; ++mt)
#pragma unroll
                for (int nt = 0; nt < 2; ++nt)
                    acc[mt][nt] = MFMA16(af[mt], bf[nt], acc[mt][nt], 0, 0, 0);
        }

        if (kk < 15) {
            __asm__ __volatile__("s_waitcnt vmcnt(0)" ::: "memory");
            __syncthreads();
        }
    }

    float bv[2];
#pragma unroll
    for (int nt = 0; nt < 2; ++nt) bv[nt] = bias[n0 + wn + nt * 16 + l15];

#pragma unroll
    for (int mt = 0; mt < 4; ++mt) {
        const int m = m0 + wm + mt * 16 + quad * 4;
#pragma unroll
        for (int nt = 0; nt < 2; ++nt) {
            const int n = n0 + wn + nt * 16 + l15;
#pragma unroll
            for (int r = 0; r < 4; ++r)
                out[(size_t)(m + r) * 1024 + n] = acc[mt][nt][r] + bv[nt];
        }
    }
}

// ---------------------------------------------------------------------------
extern "C" void kernel_launch(void* const* d_in, const int* in_sizes, int n_in,
                              void* d_out, int out_size, void* d_ws, size_t ws_size,
                              hipStream_t stream)
{
    const float* x      = (const float*)d_in[0];
    const float* qkv_w  = (const float*)d_in[2];
    const float* proj_w = (const float*)d_in[3];
    const float* proj_b = (const float*)d_in[4];
    float* out = (float*)d_out;

    const size_t SZ   = 4096 * 1024;
    const size_t WQKV = 3072 * 1024;
    const size_t WPRJ = 1024 * 1024;

    __bf16* xb      = (__bf16*)d_ws;
    __bf16* qkvwb   = xb + SZ;
    __bf16* projwb  = qkvwb + WQKV;
    __bf16* q_ws    = projwb + WPRJ;
    __bf16* k_ws    = q_ws + SZ;
    __bf16* vt_ws   = k_ws + SZ;
    __bf16* attn_ws = vt_ws + SZ;

    cvt_all<<<dim3(8192), 256, 0, stream>>>(x, qkv_w, proj_w, xb, qkvwb, projwb);
    qkv_gemm  <<<dim3(24, 32), 512, 0, stream>>>(xb, qkvwb, q_ws, k_ws, vt_ws);
    attn_kernel<<<dim3(16, 32), 512, 0, stream>>>(q_ws, k_ws, vt_ws, attn_ws);
    proj_gemm <<<dim3(16, 32), 256, 0, stream>>>(attn_ws, projwb, proj_b, out);
}

// Round 11
// 176.242 us; speedup vs baseline: 1.0478x; 1.0072x over previous
//
#include <hip/hip_runtime.h>

// ---------------------------------------------------------------------------
// Attention_52424370815683: B=2, S=2048, D=1024, H=16, hd=64. f32 I/O.
//   k0: convert x|qkv_w|proj_w f32 -> bf16 (single merged launch)
//   k1: qkv GEMM, 128x128 tile, **BK=32, 32 KB LDS dbuf -> 3 blocks/CU,
//       all 768 blocks resident (was 2/CU + 256-block tail), 24 waves/CU**.
//       512 thr / 8 waves (2Mx4N). -> q[b,h,s,d], k (pre-scaled), vT.
//   k2: flash attention (r10, banked): 512 thr / 8 waves = 4 qtiles x
//       2 keyhalves, LDS K/V dbuf per half, 32x32 swapped-QK, in-register
//       P via cvt_pk + permlane swap, split-K LDS merge. 46.4 us.
//   k3: proj GEMM, 128x64 tile, **512 thr / 8 waves (4Mx2N) -> 16 waves/CU
//       (was 8)** — same TLP lever that won attn r10 and qkv above.
// ---------------------------------------------------------------------------

typedef __bf16 bf16_8 __attribute__((ext_vector_type(8)));
typedef __bf16 bf16_4 __attribute__((ext_vector_type(4)));
typedef __bf16 bf16_2 __attribute__((ext_vector_type(2)));
typedef float floatx2 __attribute__((ext_vector_type(2)));
typedef float floatx4 __attribute__((ext_vector_type(4)));
typedef float floatx16 __attribute__((ext_vector_type(16)));
typedef unsigned uintx4 __attribute__((ext_vector_type(4)));

#define MFMA16 __builtin_amdgcn_mfma_f32_16x16x32_bf16
#define MFMA32 __builtin_amdgcn_mfma_f32_32x32x16_bf16
#define CSCALE 0.1803368801111204f   // hd^-0.5 * log2(e)
#define EXP2R  __builtin_amdgcn_exp2f   // bare v_exp_f32 (no OCML denorm fixup)

__device__ __forceinline__ void gld16(const __bf16* g, __bf16* l) {
    __builtin_amdgcn_global_load_lds(
        (const __attribute__((address_space(1))) void*)g,
        (__attribute__((address_space(3))) void*)l, 16, 0, 0);
}

// single-instruction packed f32->bf16 (RNE), lo = a, hi = b
__device__ __forceinline__ unsigned cvtpk_bf16(float a, float b) {
    unsigned d;
    __asm__("v_cvt_pk_bf16_f32 %0, %1, %2" : "=v"(d) : "v"(a), "v"(b));
    return d;
}

// v_permlane32_swap_b32: after the op, a = {a_lo, b_lo}, b = {a_hi, b_hi}
// volatile: the r2/r6/r10 (passing) form -- pinned in program order.
__device__ __forceinline__ void pl32swap(unsigned& a, unsigned& b) {
    __asm__ __volatile__("v_permlane32_swap_b32 %0, %1" : "+v"(a), "+v"(b));
}

// ---------------------------------------------------------------------------
// Kernel 0: merged f32 -> bf16 convert for x (1M f4), qkv_w (768K), proj_w
// (256K). Grid exactly 2M float4s / 256.
// ---------------------------------------------------------------------------
__global__ __launch_bounds__(256) void cvt_all(
    const float* __restrict__ x, const float* __restrict__ w1,
    const float* __restrict__ w2,
    __bf16* __restrict__ xb, __bf16* __restrict__ w1b, __bf16* __restrict__ w2b)
{
    const int i = blockIdx.x * 256 + threadIdx.x;     // float4 index
    const float* src; __bf16* dst; int off;
    if (i < (1 << 20))                  { src = x;  dst = xb;  off = i; }
    else if (i < (1 << 20) + 786432)    { src = w1; dst = w1b; off = i - (1 << 20); }
    else                                { src = w2; dst = w2b; off = i - (1 << 20) - 786432; }
    float4 v = ((const float4*)src)[off];
    bf16_4 o;
    o[0] = (__bf16)v.x; o[1] = (__bf16)v.y; o[2] = (__bf16)v.z; o[3] = (__bf16)v.w;
    ((bf16_4*)dst)[off] = o;
}

// ---------------------------------------------------------------------------
// Kernel 1: QKV GEMM. M=4096, N=3072, K=1024. grid (24,32) = 768 blocks,
// 512 threads, 8 waves (2M x 4N), 128x128 tile, BK=32, double-buffered LDS
// (32 KB -> 3 blocks/CU: ALL 768 resident, no tail; 24 waves/CU). 2-phase:
// stage(k+1) -> compute(k) -> vmcnt(0)+barrier. Staging = 1 gld16/thread
// per operand per step. q/k blocks (c<2): swapped operands -> d-contiguous
// stores. Epilogues: q/k -> [b,h,s,d] (k scaled by CSCALE), v -> vT.
// ---------------------------------------------------------------------------
__global__ __launch_bounds__(512) void qkv_gemm(
    const __bf16* __restrict__ X, const __bf16* __restrict__ W,
    __bf16* __restrict__ q_ws, __bf16* __restrict__ k_ws, __bf16* __restrict__ vt_ws)
{
    __shared__ __align__(16) __bf16 S[2][2][128 * 32];  // [buf][A/B] 32 KB

    const int tid = threadIdx.x, lane = tid & 63, wv = tid >> 6;   // wv 0..7
    const int quad = lane >> 4, l15 = lane & 15;
    const int wm = (wv >> 2) * 64, wn = (wv & 3) * 32;  // 2 x 4 wave grid
    const int m0 = blockIdx.y * 128, n0 = blockIdx.x * 128;
    const int c = n0 >> 10;                         // 0=q 1=k 2=v (block-uniform)

    // A/B row bases (both K-major, stride 1024). c<2: swapped (rows=feature).
    const __bf16* Abase;
    const __bf16* Bbase;
    if (c == 2) { Abase = X + (size_t)m0 * 1024; Bbase = W + (size_t)n0 * 1024; }
    else        { Abase = W + (size_t)n0 * 1024; Bbase = X + (size_t)m0 * 1024; }

    // staging: 128 rows x 4 chunks(8 elem) = 512 chunks = 1/thread/operand.
    // physical slot skc of row srow holds logical chunk skc^(srow&3).
    const int srow = tid >> 2, skc = tid & 3;       // srow 0..127
    const int ssw  = ((skc ^ (srow & 3)) * 8);

#define QKV_STAGE(buf, k0)                                                     \
    {                                                                          \
        gld16(Abase + srow * 1024 + (k0) + ssw, &S[buf][0][tid * 8]);          \
        gld16(Bbase + srow * 1024 + (k0) + ssw, &S[buf][1][tid * 8]);          \
    }

    floatx4 acc[4][2] = {};
    QKV_STAGE(0, 0)
    __syncthreads();

#pragma unroll 1
    for (int kk = 0; kk < 32; ++kk) {
        const int cur = kk & 1;
        if (kk < 31) QKV_STAGE(cur ^ 1, (kk + 1) * 32)

        const __bf16* As = S[cur][0];
        const __bf16* Bs = S[cur][1];
        bf16_8 af[4], bf[2];
#pragma unroll
        for (int mt = 0; mt < 4; ++mt) {
            int r = wm + mt * 16 + l15;
            af[mt] = *(const bf16_8*)&As[r * 32 + ((quad ^ (r & 3)) * 8)];
        }
#pragma unroll
        for (int nt = 0; nt < 2; ++nt) {
            int r = wn + nt * 16 + l15;
            bf[nt] = *(const bf16_8*)&Bs[r * 32 + ((quad ^ (r & 3)) * 8)];
        }
#pragma unroll
        for (int mt = 0; mt < 4; ++mt)
#pragma unroll
            for (int nt = 0; nt < 2; ++nt)
                acc[mt][nt] = MFMA16(af[mt], bf[nt], acc[mt][nt], 0, 0, 0);

        if (kk < 31) {
            __asm__ __volatile__("s_waitcnt vmcnt(0)" ::: "memory");
            __syncthreads();
        }
    }

    if (c == 2) {
        // V: D rows = token, cols = feature. Pack 4 consecutive tokens -> vT.
#pragma unroll
        for (int mt = 0; mt < 4; ++mt) {
            const int mbase = m0 + wm + mt * 16 + quad * 4;   // token, 4-aligned
            const int b = mbase >> 11, s = mbase & 2047;
#pragma unroll
            for (int nt = 0; nt < 2; ++nt) {
                const int n = n0 + wn + nt * 16 + l15;
                const int h = (n >> 6) & 15, d = n & 63;
                bf16_4 pk;
#pragma unroll
                for (int r = 0; r < 4; ++r) pk[r] = (__bf16)acc[mt][nt][r];
                *(bf16_4*)&vt_ws[((size_t)(b * 16 + h) * 64 + d) * 2048 + s] = pk;
            }
        }
    } else {
        // q/k: swapped -> D rows = feature, cols = token. d-contiguous stores.
        __bf16* dst = (c == 0) ? q_ws : k_ws;
        const float scale = (c == 1) ? CSCALE : 1.0f;
#pragma unroll
        for (int mt = 0; mt < 4; ++mt) {
            const int nn = n0 + wm + mt * 16 + quad * 4;      // feature, 4-aligned
            const int h = (nn >> 6) & 15, d0 = nn & 63;
#pragma unroll
            for (int nt = 0; nt < 2; ++nt) {
                const int token = m0 + wn + nt * 16 + l15;
                const int b = token >> 11, skey = token & 2047;
                bf16_4 pk;
#pragma unroll
                for (int r = 0; r < 4; ++r) pk[r] = (__bf16)(acc[mt][nt][r] * scale);
                *(bf16_4*)&dst[((size_t)(b * 16 + h) * 2048 + skey) * 64 + d0] = pk;
            }
        }
    }
#undef QKV_STAGE
}

// ---------------------------------------------------------------------------
// Kernel 2: flash attention (r10, banked). grid (16 qt, 32 bh) remapped
// (linear%8 = XCD owns 4 bh). 512 thr / 8 waves: qtile = w&3, keyhalf =
// w>>2. Each wave: 32 q x 1024 keys = 16 tiles from its half's dbuf LDS
// K/V (staged by the half's 256 threads, shared by 4 waves -> VGPR 64 ->
// high occupancy). Per tile: QK (8 MFMA32, fzero C-in), fused per-s
// {exp/pack -> permlane swap -> 2 PV MFMA}. Split-K merge via LDS overlay.
// ---------------------------------------------------------------------------
__global__ __launch_bounds__(512, 4) void attn_kernel(
    const __bf16* __restrict__ q_ws, const __bf16* __restrict__ k_ws,
    const __bf16* __restrict__ vt_ws, __bf16* __restrict__ attn_ws)
{
    __shared__ __align__(16) __bf16 Ks [2][2][64 * 64];   // [half][buf] 32 KB
    __shared__ __align__(16) __bf16 Vts[2][2][64 * 64];   // [half][buf] 32 KB

    const int tid = threadIdx.x, lane = tid & 63, w = tid >> 6;   // w 0..7
    const int l31 = lane & 31, hi = lane >> 5;
    const int qtile = w & 3, keyhalf = w >> 2;
    const int htid = tid & 255;                     // thread within half

    // XCD remap: linear = bx + 16*by in [0,512); XCD = linear%8 owns 4 bh.
    const int linear = blockIdx.x + (blockIdx.y << 4);
    const int r = linear >> 3;                      // 0..63
    const int bh = ((linear & 7) << 2) + (r & 3);
    const int qt = r >> 2;                          // 0..15
    const int q0 = qt * 128 + qtile * 32;

    const __bf16* __restrict__ qp  = q_ws  + (size_t)bh * (2048 * 64);
    const __bf16* __restrict__ kp  = k_ws  + (size_t)bh * (2048 * 64);
    const __bf16* __restrict__ vtp = vt_ws + (size_t)bh * (64 * 2048);
    const int koff = keyhalf * 1024;                // this half's key base

    // staging: loop-invariant per-lane bases
    const int srow = htid >> 3, skc = htid & 7;     // srow 0..31
    const int sw   = (skc ^ (srow & 7)) * 8;
    const __bf16* kb0 = kp  + (size_t)(koff + srow) * 64 + sw;
    const __bf16* kb1 = kp  + (size_t)(koff + srow + 32) * 64 + sw;
    const __bf16* vb0 = vtp + (size_t)srow * 2048 + koff + sw;
    const __bf16* vb1 = vtp + (size_t)(srow + 32) * 2048 + koff + sw;
    const int ldsoff = htid * 8;                    // wave-uniform + lane*16B

    // Q B-frags (4 k-steps of 16), held in registers all loop
    bf16_8 qf[4];
    {
        const int qrow = q0 + l31;
#pragma unroll
        for (int s = 0; s < 4; ++s)
            qf[s] = *(const bf16_8*)&qp[qrow * 64 + s * 16 + hi * 8];
    }

    floatx16 oacc[2] = {};                  // [d-tile] O^T accumulators
    floatx2 ls2[4] = {};                    // packed row-sum partials
    const floatx16 fzero = {};              // persistent zero C-in (hoisted)

    // prologue: stage tile 0 into buf 0
    gld16(kb0, &Ks [keyhalf][0][ldsoff]);
    gld16(kb1, &Ks [keyhalf][0][ldsoff + 2048]);
    gld16(vb0, &Vts[keyhalf][0][ldsoff]);
    gld16(vb1, &Vts[keyhalf][0][ldsoff + 2048]);
    __syncthreads();                        // drains vmcnt(0): buf0 ready

#pragma unroll 1
    for (int kt = 0; kt < 16; ++kt) {
        const int cur = kt & 1;
        // ---- issue next tile's stage FIRST (hidden under compute)
        if (kt < 15) {
            const int ko = (kt + 1) * 64;
            gld16(kb0 + ko * 64, &Ks [keyhalf][cur ^ 1][ldsoff]);
            gld16(kb1 + ko * 64, &Ks [keyhalf][cur ^ 1][ldsoff + 2048]);
            gld16(vb0 + ko,      &Vts[keyhalf][cur ^ 1][ldsoff]);
            gld16(vb1 + ko,      &Vts[keyhalf][cur ^ 1][ldsoff + 2048]);
        }
        const __bf16* Kb = Ks [keyhalf][cur];
        const __bf16* Vb = Vts[keyhalf][cur];

        // ---- S^T[64 key][32 q]: 2 key-subtiles x 4 k-steps
        floatx16 sacc[2];
        __builtin_amdgcn_s_setprio(1);
        {
            const int kc0 = hi;
            const int r0 = l31, r1 = 32 + l31;
            bf16_8 kf0 = *(const bf16_8*)&Kb[r0 * 64 + ((kc0 ^ (r0 & 7)) * 8)];
            bf16_8 kf1 = *(const bf16_8*)&Kb[r1 * 64 + ((kc0 ^ (r1 & 7)) * 8)];
            sacc[0] = MFMA32(kf0, qf[0], fzero, 0, 0, 0);
            sacc[1] = MFMA32(kf1, qf[0], fzero, 0, 0, 0);
        }
#pragma unroll
        for (int s = 1; s < 4; ++s) {
            const int kc = s * 2 + hi;
#pragma unroll
            for (int t = 0; t < 2; ++t) {
                const int row = t * 32 + l31;
                bf16_8 kf = *(const bf16_8*)&Kb[row * 64 + ((kc ^ (row & 7)) * 8)];
                sacc[t] = MFMA32(kf, qf[s], sacc[t], 0, 0, 0);
            }
        }
        __builtin_amdgcn_s_setprio(0);

        // ---- fused per-s: exp/pack quarter -> permlane swap -> 2 PV MFMAs
#pragma unroll
        for (int s = 0; s < 4; ++s) {
            const int t = s >> 1, b2 = (s & 1) * 2;
            unsigned Dw[4];                 // [jrel*2+e], j = b2+jrel
#pragma unroll
            for (int jr = 0; jr < 2; ++jr)
#pragma unroll
                for (int e = 0; e < 2; ++e) {
                    const int j = b2 + jr;
                    float pa = EXP2R(sacc[t][j * 4 + e * 2]);
                    float pb = EXP2R(sacc[t][j * 4 + e * 2 + 1]);
                    floatx2 p2; p2[0] = pa; p2[1] = pb;
                    ls2[t * 2 + e] += p2;        // v_pk_add_f32
                    Dw[jr * 2 + e] = cvtpk_bf16(pa, pb);
                }
            unsigned x0 = Dw[0], y0 = Dw[2];
            unsigned x1 = Dw[1], y1 = Dw[3];
            pl32swap(x0, y0);
            pl32swap(x1, y1);
            uintx4 uu; uu[0] = x0; uu[1] = x1; uu[2] = y0; uu[3] = y1;
            const bf16_8 pf = __builtin_bit_cast(bf16_8, uu);
            const int kc = s * 2 + hi;
            __builtin_amdgcn_s_setprio(1);
#pragma unroll
            for (int dt = 0; dt < 2; ++dt) {
                const int drow = dt * 32 + l31;
                bf16_8 vf = *(const bf16_8*)&Vb[drow * 64 + ((kc ^ (drow & 7)) * 8)];
                oacc[dt] = MFMA32(vf, pf, oacc[dt], 0, 0, 0);
            }
            __builtin_amdgcn_s_setprio(0);
        }

        // ---- single barrier per tile: stage loads drained + buf reads done
        if (kt < 15) {
            __asm__ __volatile__("s_waitcnt vmcnt(0)" ::: "memory");
            __syncthreads();
        }
    }

    // ---- this wave's row-sums over its 1024 keys (combine hi halves)
    const floatx2 lv = (ls2[0] + ls2[1]) + (ls2[2] + ls2[3]);
    const float lsum = lv[0] + lv[1];
    const float lw = lsum + __shfl_xor(lsum, 32, 64);

    // ---- split-K merge (LDS overlay on K/V buffers; all reads done)
    __syncthreads();
    floatx4* comb  = (floatx4*)&Ks[0][0][0];    // [qtile][8][64] = 32 KB exact
    float*   lcomb = (float*)&Vts[0][0][0];     // [qtile][64] = 1 KB

    if (keyhalf == 1) {
#pragma unroll
        for (int dt = 0; dt < 2; ++dt)
#pragma unroll
            for (int g = 0; g < 4; ++g) {
                floatx4 v4;
#pragma unroll
                for (int r4 = 0; r4 < 4; ++r4) v4[r4] = oacc[dt][g * 4 + r4];
                comb[((qtile * 8 + dt * 4 + g) << 6) + lane] = v4;
            }
        lcomb[(qtile << 6) + lane] = lw;
    }
    __syncthreads();
    if (keyhalf == 0) {
        // oacc C32 layout: col = q = lane&31, row d = (r&3)+8*(r>>2)+4*hi.
        const int b = bh >> 4, h = bh & 15;
        const float inv_l = 1.0f / (lw + lcomb[(qtile << 6) + lane]);
        const int token = b * 2048 + q0 + l31;
#pragma unroll
        for (int dt = 0; dt < 2; ++dt)
#pragma unroll
            for (int g = 0; g < 4; ++g) {
                const floatx4 v2 = comb[((qtile * 8 + dt * 4 + g) << 6) + lane];
                bf16_4 ok;
#pragma unroll
                for (int r4 = 0; r4 < 4; ++r4)
                    ok[r4] = (__bf16)((oacc[dt][g * 4 + r4] + v2[r4]) * inv_l);
                *(bf16_4*)&attn_ws[(size_t)token * 1024 + h * 64 + dt * 32 + g * 8 + hi * 4] = ok;
            }
    }
}

// ---------------------------------------------------------------------------
// Kernel 3: proj GEMM + bias -> f32 out. M=4096, N=1024, K=1024.
// 128x64 tiles, grid (16, 32) = 512 blocks, **512 threads / 8 waves
// (4M x 2N, acc 2x2) -> 16 waves/CU (4/SIMD)** — double the TLP to cover
// the 2-phase barrier drain. 48 KB LDS dbuf -> 2 blocks/CU.
// ---------------------------------------------------------------------------
__device__ __forceinline__ void proj_stage(
    const __bf16* __restrict__ A, const __bf16* __restrict__ Bp,
    int k0, __bf16* As, __bf16* Bs, int tid)
{
    const int srow = tid >> 3, skc = tid & 7;          // srow 0..63
    const int ssw  = (skc ^ (srow & 7)) * 8;
#pragma unroll
    for (int it = 0; it < 2; ++it) {                   // A: 128 rows
        const int row = srow + it * 64;
        gld16(A + row * 1024 + k0 + ssw, &As[(it * 512 + tid) * 8]);
    }
    gld16(Bp + srow * 1024 + k0 + ssw, &Bs[tid * 8]);  // B: 64 rows
}

__global__ __launch_bounds__(512) void proj_gemm(
    const __bf16* __restrict__ Ain, const __bf16* __restrict__ W,
    const float* __restrict__ bias, float* __restrict__ out)
{
    __shared__ __align__(16) __bf16 As[2][128 * 64];   // [buf][m][k] swizzled
    __shared__ __align__(16) __bf16 Bs[2][64 * 64];    // [buf][n][k] swizzled
    floatx4 acc[2][2] = {};
    const int m0 = blockIdx.y * 128, n0 = blockIdx.x * 64;

    const int tid = threadIdx.x, lane = tid & 63, wv = tid >> 6;   // wv 0..7
    const int quad = lane >> 4, l15 = lane & 15;
    const int wm = (wv >> 1) * 32, wn = (wv & 1) * 32; // 4 x 2 wave grid

    const __bf16* A  = Ain + (size_t)m0 * 1024;
    const __bf16* Bp = W   + (size_t)n0 * 1024;

    proj_stage(A, Bp, 0, As[0], Bs[0], tid);
    __syncthreads();

#pragma unroll 1
    for (int kk = 0; kk < 16; ++kk) {
        const int cur = kk & 1;
        if (kk < 15)
            proj_stage(A, Bp, (kk + 1) * 64, As[cur ^ 1], Bs[cur ^ 1], tid);

        const __bf16* Ab = As[cur];
        const __bf16* Bb = Bs[cur];
#pragma unroll
        for (int ks = 0; ks < 2; ++ks) {
            bf16_8 af[2], bf[2];
#pragma unroll
            for (int mt = 0; mt < 2; ++mt) {
                int r = wm + mt * 16 + l15;
                af[mt] = *(const bf16_8*)&Ab[r * 64 + (((ks * 4 + quad) ^ (r & 7)) * 8)];
            }
#pragma unroll
            for (int nt = 0; nt < 2; ++nt) {
                int r = wn + nt * 16 + l15;
                bf[nt] = *(const bf16_8*)&Bb[r * 64 + (((ks * 4 + quad) ^ (r & 7)) * 8)];
            }
#pragma unroll
            for (int mt = 0; mt < 2; ++mt)
#pragma unroll
                for (int nt = 0; nt < 2; ++nt)
                    acc[mt][nt] = MFMA16(af[mt], bf[nt], acc[mt][nt], 0, 0, 0);
        }

        if (kk < 15) {
            __asm__ __volatile__("s_waitcnt vmcnt(0)" ::: "memory");
            __syncthreads();
        }
    }

    float bv[2];
#pragma unroll
    for (int nt = 0; nt < 2; ++nt) bv[nt] = bias[n0 + wn + nt * 16 + l15];

#pragma unroll
    for (int mt = 0; mt < 2; ++mt) {
        const int m = m0 + wm + mt * 16 + quad * 4;
#pragma unroll
        for (int nt = 0; nt < 2; ++nt) {
            const int n = n0 + wn + nt * 16 + l15;
#pragma unroll
            for (int r = 0; r < 4; ++r)
                out[(size_t)(m + r) * 1024 + n] = acc[mt][nt][r] + bv[nt];
        }
    }
}

// ---------------------------------------------------------------------------
extern "C" void kernel_launch(void* const* d_in, const int* in_sizes, int n_in,
                              void* d_out, int out_size, void* d_ws, size_t ws_size,
                              hipStream_t stream)
{
    const float* x      = (const float*)d_in[0];
    const float* qkv_w  = (const float*)d_in[2];
    const float* proj_w = (const float*)d_in[3];
    const float* proj_b = (const float*)d_in[4];
    float* out = (float*)d_out;

    const size_t SZ   = 4096 * 1024;
    const size_t WQKV = 3072 * 1024;
    const size_t WPRJ = 1024 * 1024;

    __bf16* xb      = (__bf16*)d_ws;
    __bf16* qkvwb   = xb + SZ;
    __bf16* projwb  = qkvwb + WQKV;
    __bf16* q_ws    = projwb + WPRJ;
    __bf16* k_ws    = q_ws + SZ;
    __bf16* vt_ws   = k_ws + SZ;
    __bf16* attn_ws = vt_ws + SZ;

    cvt_all<<<dim3(8192), 256, 0, stream>>>(x, qkv_w, proj_w, xb, qkvwb, projwb);
    qkv_gemm  <<<dim3(24, 32), 512, 0, stream>>>(xb, qkvwb, q_ws, k_ws, vt_ws);
    attn_kernel<<<dim3(16, 32), 512, 0, stream>>>(q_ws, k_ws, vt_ws, attn_ws);
    proj_gemm <<<dim3(16, 32), 512, 0, stream>>>(attn_ws, projwb, proj_b, out);
}